// Round 1
// baseline (555.835 us; speedup 1.0000x reference)
//
#include <hip/hip_runtime.h>

// Deformable depthwise 3x3 conv, B=8 C=256 H=W=96, stride=1 pad=1 dil=1, fp32.
// Key facts: offsets shared across channels -> bilinear params computed once
// per (pixel,tap) in registers, reused over a 32-channel loop. Validity and
// corner-select logic folded into pre-permuted weights so the per-channel
// inner loop is 2 paired loads + 5 FMA per tap.

constexpr int B_ = 8, C_ = 256, H_ = 96, W_ = 96;
constexpr int HW_ = H_ * W_;
constexpr int TH = 4;              // rows per block
constexpr int NTHREADS = TH * W_;  // 384 = 6 waves
constexpr int CSPLIT = 8;          // channel splits across grid.z
constexpr int CPB = C_ / CSPLIT;   // 32 channels per block

__device__ __forceinline__ float2 ld2(const float* p) {
    float2 v;
    __builtin_memcpy(&v, p, sizeof(float2));  // 4B-aligned 8B load
    return v;
}

__global__ __launch_bounds__(NTHREADS) void deform_dw_conv(
    const float* __restrict__ x, const float* __restrict__ off,
    const float* __restrict__ wgt, const float* __restrict__ bias,
    float* __restrict__ out)
{
    const int tid  = threadIdx.x;
    const int r    = tid / W_;
    const int wcol = tid - r * W_;
    const int h    = blockIdx.x * TH + r;
    const int b    = blockIdx.y;
    const int c0   = blockIdx.z * CPB;

    const float* offp = off + (size_t)b * 18 * HW_ + (size_t)h * W_ + wcol;

    // Per-(pixel,tap) params: 4 weights pre-permuted onto the loaded positions
    // [A.x=(yc,xc), A.y=(yc,xc+1), B.x=(yc+1,xc), B.y=(yc+1,xc+1)], plus the
    // element offset of (yc,xc) inside the plane.
    float cw[9][4];
    int goff[9];

#pragma unroll
    for (int kk = 0; kk < 9; ++kk) {
        const int i = kk / 3, j = kk % 3;
        const float py = (float)(h - 1 + i) + offp[(2 * kk) * HW_];
        const float px = (float)(wcol - 1 + j) + offp[(2 * kk + 1) * HW_];
        const float fy = floorf(py), fx = floorf(px);
        const float wy = py - fy, wx = px - fx;
        const int y0 = (int)fy, x0 = (int)fx;
        const bool vy0 = (unsigned)y0 < (unsigned)H_;
        const bool vy1 = (unsigned)(y0 + 1) < (unsigned)H_;
        const bool vx0 = (unsigned)x0 < (unsigned)W_;
        const bool vx1 = (unsigned)(x0 + 1) < (unsigned)W_;
        // validity folded into the bilinear weights
        const float w00 = (vy0 && vx0) ? (1.f - wy) * (1.f - wx) : 0.f;
        const float w01 = (vy0 && vx1) ? (1.f - wy) * wx : 0.f;
        const float w10 = (vy1 && vx0) ? wy * (1.f - wx) : 0.f;
        const float w11 = (vy1 && vx1) ? wy * wx : 0.f;
        const int yc = min(max(y0, 0), H_ - 2);
        const int xc = min(max(x0, 0), W_ - 2);
        const bool rs = (y0 == yc);   // y0 maps to row A (else row B / dead)
        const bool cs = (x0 == xc);   // x0 maps to col lo (else hi / dead)
        // Permute corner weights onto loaded positions; invalid corners have
        // weight 0, so "don't care" placements are harmless.
        cw[kk][0] = rs ? (cs ? w00 : w01) : (cs ? w10 : w11); // A.x
        cw[kk][1] = rs ? (cs ? w01 : w00) : (cs ? w11 : w10); // A.y
        cw[kk][2] = rs ? (cs ? w10 : w11) : (cs ? w00 : w01); // B.x
        cw[kk][3] = rs ? (cs ? w11 : w10) : (cs ? w01 : w00); // B.y
        goff[kk] = yc * W_ + xc;
    }

    const int pix = h * W_ + wcol;
#pragma unroll 1
    for (int c = c0; c < c0 + CPB; ++c) {
        const float* xp = x + (size_t)(b * C_ + c) * HW_;
        float acc = 0.f;
#pragma unroll
        for (int kk = 0; kk < 9; ++kk) {
            const float2 pA = ld2(xp + goff[kk]);
            const float2 pB = ld2(xp + goff[kk] + W_);
            float s = cw[kk][0] * pA.x;
            s = fmaf(cw[kk][1], pA.y, s);
            s = fmaf(cw[kk][2], pB.x, s);
            s = fmaf(cw[kk][3], pB.y, s);
            acc = fmaf(wgt[c * 9 + kk], s, acc);
        }
        out[(size_t)(b * C_ + c) * HW_ + pix] = acc + bias[c];
    }
}

extern "C" void kernel_launch(void* const* d_in, const int* in_sizes, int n_in,
                              void* d_out, int out_size, void* d_ws, size_t ws_size,
                              hipStream_t stream) {
    const float* x    = (const float*)d_in[0];
    const float* off  = (const float*)d_in[1];
    const float* w    = (const float*)d_in[2];
    const float* bias = (const float*)d_in[3];
    float* out        = (float*)d_out;
    dim3 grid(H_ / TH, B_, CSPLIT);
    deform_dw_conv<<<grid, NTHREADS, 0, stream>>>(x, off, w, bias, out);
}

// Round 2
// 451.814 us; speedup vs baseline: 1.2302x; 1.2302x over previous
//
#include <hip/hip_runtime.h>

// Deformable depthwise 3x3 conv, B=8 C=256 H=W=96, stride=1 pad=1 dil=1, fp32.
// R1 post-mortem: loads were serialized (VGPR=68 -> compiler sank each load
// next to its FMA, ~215 cyc/load). R2: explicit gather-then-compute phases,
// channels unrolled x2 -> 36 loads in flight per wave before any wait.

constexpr int B_ = 8, C_ = 256, H_ = 96, W_ = 96;
constexpr int HW_ = H_ * W_;
constexpr int TH = 4;              // rows per block
constexpr int NTHREADS = TH * W_;  // 384 = 6 waves
constexpr int CSPLIT = 8;          // channel splits across grid.z
constexpr int CPB = C_ / CSPLIT;   // 32 channels per block

__device__ __forceinline__ float2 ld2(const float* p) {
    float2 v;
    __builtin_memcpy(&v, p, sizeof(float2));  // 4B-aligned 8B load
    return v;
}

__global__ __launch_bounds__(NTHREADS) void deform_dw_conv(
    const float* __restrict__ x, const float* __restrict__ off,
    const float* __restrict__ wgt, const float* __restrict__ bias,
    float* __restrict__ out)
{
    const int tid  = threadIdx.x;
    const int r    = tid / W_;
    const int wcol = tid - r * W_;
    const int h    = blockIdx.x * TH + r;
    const int b    = blockIdx.y;
    const int c0   = blockIdx.z * CPB;

    const float* offp = off + (size_t)b * 18 * HW_ + (size_t)h * W_ + wcol;

    // Per-(pixel,tap) params: 4 weights pre-permuted onto the loaded positions
    // [A.x=(yc,xc), A.y=(yc,xc+1), B.x=(yc+1,xc), B.y=(yc+1,xc+1)], plus the
    // element offset of (yc,xc) inside the plane.
    float cw[9][4];
    int goff[9];

#pragma unroll
    for (int kk = 0; kk < 9; ++kk) {
        const int i = kk / 3, j = kk % 3;
        const float py = (float)(h - 1 + i) + offp[(2 * kk) * HW_];
        const float px = (float)(wcol - 1 + j) + offp[(2 * kk + 1) * HW_];
        const float fy = floorf(py), fx = floorf(px);
        const float wy = py - fy, wx = px - fx;
        const int y0 = (int)fy, x0 = (int)fx;
        const bool vy0 = (unsigned)y0 < (unsigned)H_;
        const bool vy1 = (unsigned)(y0 + 1) < (unsigned)H_;
        const bool vx0 = (unsigned)x0 < (unsigned)W_;
        const bool vx1 = (unsigned)(x0 + 1) < (unsigned)W_;
        // validity folded into the bilinear weights
        const float w00 = (vy0 && vx0) ? (1.f - wy) * (1.f - wx) : 0.f;
        const float w01 = (vy0 && vx1) ? (1.f - wy) * wx : 0.f;
        const float w10 = (vy1 && vx0) ? wy * (1.f - wx) : 0.f;
        const float w11 = (vy1 && vx1) ? wy * wx : 0.f;
        const int yc = min(max(y0, 0), H_ - 2);
        const int xc = min(max(x0, 0), W_ - 2);
        const bool rs = (y0 == yc);   // y0 maps to row A (else row B / dead)
        const bool cs = (x0 == xc);   // x0 maps to col lo (else hi / dead)
        cw[kk][0] = rs ? (cs ? w00 : w01) : (cs ? w10 : w11); // A.x
        cw[kk][1] = rs ? (cs ? w01 : w00) : (cs ? w11 : w10); // A.y
        cw[kk][2] = rs ? (cs ? w10 : w11) : (cs ? w00 : w01); // B.x
        cw[kk][3] = rs ? (cs ? w11 : w10) : (cs ? w01 : w00); // B.y
        goff[kk] = yc * W_ + xc;
    }

    const int pix = h * W_ + wcol;

#pragma unroll 1
    for (int c = c0; c < c0 + CPB; c += 2) {
        const float* xp0 = x + (size_t)(b * C_ + c) * HW_;
        const float* xp1 = xp0 + HW_;

        // ---- gather phase: 36 independent loads, one vmcnt window ----
        float2 A0[9], Bb0[9], A1[9], Bb1[9];
#pragma unroll
        for (int kk = 0; kk < 9; ++kk) {
            A0[kk]  = ld2(xp0 + goff[kk]);
            Bb0[kk] = ld2(xp0 + goff[kk] + W_);
            A1[kk]  = ld2(xp1 + goff[kk]);
            Bb1[kk] = ld2(xp1 + goff[kk] + W_);
        }

        // ---- compute phase ----
        float acc0 = 0.f, acc1 = 0.f;
#pragma unroll
        for (int kk = 0; kk < 9; ++kk) {
            float s0 = cw[kk][0] * A0[kk].x;
            s0 = fmaf(cw[kk][1], A0[kk].y, s0);
            s0 = fmaf(cw[kk][2], Bb0[kk].x, s0);
            s0 = fmaf(cw[kk][3], Bb0[kk].y, s0);
            acc0 = fmaf(wgt[c * 9 + kk], s0, acc0);
            float s1 = cw[kk][0] * A1[kk].x;
            s1 = fmaf(cw[kk][1], A1[kk].y, s1);
            s1 = fmaf(cw[kk][2], Bb1[kk].x, s1);
            s1 = fmaf(cw[kk][3], Bb1[kk].y, s1);
            acc1 = fmaf(wgt[(c + 1) * 9 + kk], s1, acc1);
        }
        out[(size_t)(b * C_ + c) * HW_ + pix]       = acc0 + bias[c];
        out[(size_t)(b * C_ + c + 1) * HW_ + pix]   = acc1 + bias[c + 1];
    }
}

extern "C" void kernel_launch(void* const* d_in, const int* in_sizes, int n_in,
                              void* d_out, int out_size, void* d_ws, size_t ws_size,
                              hipStream_t stream) {
    const float* x    = (const float*)d_in[0];
    const float* off  = (const float*)d_in[1];
    const float* w    = (const float*)d_in[2];
    const float* bias = (const float*)d_in[3];
    float* out        = (float*)d_out;
    dim3 grid(H_ / TH, B_, CSPLIT);
    deform_dw_conv<<<grid, NTHREADS, 0, stream>>>(x, off, w, bias, out);
}

// Round 3
// 266.944 us; speedup vs baseline: 2.0822x; 1.6925x over previous
//
#include <hip/hip_runtime.h>

// Deformable depthwise 3x3 conv, B=8 C=256 H=W=96, fp32.
// R2 post-mortem: gather is L1-transaction-bound (~42 cyc per wave-gather;
// per-lane y-jitter scatters each wave over ~6 rows -> ~20 64B lines per
// instruction). R3: stage the block's row window in LDS per channel and
// gather from LDS (4B bank granularity, 2 lanes/bank is free). Row window
// [rmin,rmax] computed exactly per block (LDS atomic min/max) -> correct for
// unbounded offsets. Staging loads issued before the barrier so global
// latency overlaps the previous channel's gather.

constexpr int B_ = 8, C_ = 256, H_ = 96, W_ = 96;
constexpr int HW_ = H_ * W_;
constexpr int TH = 4;              // pixel rows per block
constexpr int NT = TH * W_;        // 384 threads = 6 waves
constexpr int CSPLIT = 8;
constexpr int CPB = C_ / CSPLIT;   // 32 channels per block
constexpr int LSTR = 100;          // LDS row stride (floats): 16B-aligned rows,
                                   // bank=(4*row+col)%32 spreads rows over banks
constexpr int LDS_ELEMS = 96 * LSTR;  // worst case all 96 rows: 38400 B

__global__ __launch_bounds__(NT) void deform_dw_conv(
    const float* __restrict__ x, const float* __restrict__ off,
    const float* __restrict__ wgt, const float* __restrict__ bias,
    float* __restrict__ out)
{
    __shared__ float lx[LDS_ELEMS];
    __shared__ int s_rmin, s_rmax;

    const int tid  = threadIdx.x;
    const int r    = tid / W_;
    const int wcol = tid - r * W_;
    const int h    = blockIdx.x * TH + r;
    const int b    = blockIdx.y;
    const int c0   = blockIdx.z * CPB;

    if (tid == 0) { s_rmin = H_; s_rmax = -1; }
    __syncthreads();

    const float* offp = off + (size_t)b * 18 * HW_ + (size_t)h * W_ + wcol;

    // Per-(pixel,tap) params: 4 weights pre-permuted onto loaded positions
    // [A.x=(yc,xc), A.y=(yc,xc+1), B.x=(yc+1,xc), B.y=(yc+1,xc+1)]; validity
    // folded into weights so invalid corners multiply by 0.
    float cw[9][4];
    int lofs[9];
    int myrmin = H_, myrmax = -1;

#pragma unroll
    for (int kk = 0; kk < 9; ++kk) {
        const int i = kk / 3, j = kk % 3;
        const float py = (float)(h - 1 + i) + offp[(2 * kk) * HW_];
        const float px = (float)(wcol - 1 + j) + offp[(2 * kk + 1) * HW_];
        const float fy = floorf(py), fx = floorf(px);
        const float wy = py - fy, wx = px - fx;
        const int y0 = (int)fy, x0 = (int)fx;
        const bool vy0 = (unsigned)y0 < (unsigned)H_;
        const bool vy1 = (unsigned)(y0 + 1) < (unsigned)H_;
        const bool vx0 = (unsigned)x0 < (unsigned)W_;
        const bool vx1 = (unsigned)(x0 + 1) < (unsigned)W_;
        const float w00 = (vy0 && vx0) ? (1.f - wy) * (1.f - wx) : 0.f;
        const float w01 = (vy0 && vx1) ? (1.f - wy) * wx : 0.f;
        const float w10 = (vy1 && vx0) ? wy * (1.f - wx) : 0.f;
        const float w11 = (vy1 && vx1) ? wy * wx : 0.f;
        const int yc = min(max(y0, 0), H_ - 2);
        const int xc = min(max(x0, 0), W_ - 2);
        const bool rs = (y0 == yc);
        const bool cs = (x0 == xc);
        cw[kk][0] = rs ? (cs ? w00 : w01) : (cs ? w10 : w11);
        cw[kk][1] = rs ? (cs ? w01 : w00) : (cs ? w11 : w10);
        cw[kk][2] = rs ? (cs ? w10 : w11) : (cs ? w00 : w01);
        cw[kk][3] = rs ? (cs ? w11 : w10) : (cs ? w01 : w00);
        lofs[kk] = yc * LSTR + xc;
        myrmin = min(myrmin, yc);
        myrmax = max(myrmax, yc);
    }
    atomicMin(&s_rmin, myrmin);
    atomicMax(&s_rmax, myrmax);
    __syncthreads();
    const int rmin  = s_rmin;
    const int nrows = s_rmax + 2 - rmin;   // stage rows [rmin, rmax+1]
    const int n4    = nrows * (W_ / 4);    // float4 count (contiguous global span)
#pragma unroll
    for (int kk = 0; kk < 9; ++kk) lofs[kk] -= rmin * LSTR;

    const int pix = h * W_ + wcol;
    const int myrow = tid / (W_ / 4);          // staging dest for e4 = tid
    const int mycol = (tid - myrow * (W_ / 4)) * 4;

#pragma unroll 1
    for (int c = c0; c < c0 + CPB; ++c) {
        const float* xp = x + (size_t)(b * C_ + c) * HW_ + rmin * W_;

        // Prefetch this channel's window BEFORE the barrier: global latency
        // overlaps the previous channel's gather phase.
        float4 pf;
        if (tid < n4) __builtin_memcpy(&pf, xp + 4 * tid, sizeof(float4));

        __syncthreads();   // previous gather done; safe to overwrite LDS
        if (tid < n4)
            *(float4*)&lx[myrow * LSTR + mycol] = pf;
        for (int e4 = tid + NT; e4 < n4; e4 += NT) {   // rare: nrows > 16
            const int row = e4 / (W_ / 4);
            const int col = (e4 - row * (W_ / 4)) * 4;
            float4 v;
            __builtin_memcpy(&v, xp + 4 * e4, sizeof(float4));
            *(float4*)&lx[row * LSTR + col] = v;
        }
        __syncthreads();

        float acc = 0.f;
#pragma unroll
        for (int kk = 0; kk < 9; ++kk) {
            const float a0 = lx[lofs[kk]];
            const float a1 = lx[lofs[kk] + 1];
            const float b0 = lx[lofs[kk] + LSTR];
            const float b1 = lx[lofs[kk] + LSTR + 1];
            float s = cw[kk][0] * a0;
            s = fmaf(cw[kk][1], a1, s);
            s = fmaf(cw[kk][2], b0, s);
            s = fmaf(cw[kk][3], b1, s);
            acc = fmaf(wgt[c * 9 + kk], s, acc);
        }
        out[(size_t)(b * C_ + c) * HW_ + pix] = acc + bias[c];
    }
}

extern "C" void kernel_launch(void* const* d_in, const int* in_sizes, int n_in,
                              void* d_out, int out_size, void* d_ws, size_t ws_size,
                              hipStream_t stream) {
    const float* x    = (const float*)d_in[0];
    const float* off  = (const float*)d_in[1];
    const float* w    = (const float*)d_in[2];
    const float* bias = (const float*)d_in[3];
    float* out        = (float*)d_out;
    dim3 grid(H_ / TH, B_, CSPLIT);
    deform_dw_conv<<<grid, NT, 0, stream>>>(x, off, w, bias, out);
}